// Round 4
// baseline (754.241 us; speedup 1.0000x reference)
//
#include <hip/hip_runtime.h>

#define E_TOT 1600000
#define N_AT  50000

typedef unsigned short u16;
typedef __attribute__((ext_vector_type(8))) __bf16 bf16x8;
typedef __attribute__((ext_vector_type(4))) __bf16 bf16x4;
typedef __attribute__((ext_vector_type(4))) float f32x4;

// Workspace layout (byte offsets), all 16B-aligned:
//   [0,       1024)   sums1 (256 f32)  -- zeroed by k_setup
//   [1024,    1536)   sums2 (128 f32)  -- zeroed by k_setup
//   [2048,   43008)   wf    (20480 bf16, B-fragment order) -- written by k_setup
//   [43008, +12.8M)   ns    (N*64 f32) -- zeroed by k_setup
//   [+,      +6.4M)   ab    (N*64 bf16) -- written by k_setup
//   [+, 409.6M or 102.4M)  U (E*128 bf16, frag layout; big path)
//                          / nbrb (E*32 bf16; fallback path)
#define SUM1_OFF 0
#define SUM2_OFF 1024
#define WF_OFF   2048
#define NS_OFF   43008
#define AB_OFF   12843008
#define U_OFF    19243008
#define NBRB_OFF 19243008
#define WS_BIG   428843008ULL   // U path
#define WS_FULL  121643008ULL   // fallback nbrb path (proven available)

__device__ __forceinline__ u16 f2bf(float f) {
    unsigned int u = __float_as_uint(f);
    return (u16)((u + 0x7FFFu + ((u >> 16) & 1u)) >> 16);
}
__device__ __forceinline__ float softplus_f(float x) {
    return fmaxf(x, 0.0f) + __logf(1.0f + __expf(-fabsf(x)));
}
__device__ __forceinline__ bf16x8 cvt8v(f32x4 a, f32x4 b) {
    bf16x8 r;
    r[0] = (__bf16)a[0]; r[1] = (__bf16)a[1]; r[2] = (__bf16)a[2]; r[3] = (__bf16)a[3];
    r[4] = (__bf16)b[0]; r[5] = (__bf16)b[1]; r[6] = (__bf16)b[2]; r[7] = (__bf16)b[3];
    return r;
}

// ---------------------------------------------------------------------------
// k_setup: zero sums1/sums2/ns + cvt atom->ab + swizzle W->wf
// ---------------------------------------------------------------------------
__global__ __launch_bounds__(256) void k_setup(const float* __restrict__ atom,
                                               const float* __restrict__ W,
                                               char* __restrict__ ws) {
    u16* wf   = (u16*)(ws + WF_OFF);
    float* ns = (float*)(ws + NS_OFF);
    u16* ab   = (u16*)(ws + AB_OFF);
    const int tid = blockIdx.x * 256 + threadIdx.x;
    const int gsz = gridDim.x * 256;

    for (int i = tid; i < 512; i += gsz) ((float*)ws)[i] = 0.0f;  // sums1+sums2

    f32x4 z = {0.f, 0.f, 0.f, 0.f};
    for (int i = tid; i < N_AT * 64 / 4; i += gsz) ((f32x4*)ns)[i] = z;

    for (int i = tid; i < N_AT * 64 / 4; i += gsz) {
        f32x4 v = ((const f32x4*)atom)[i];
        bf16x4 h;
        h[0] = (__bf16)v[0]; h[1] = (__bf16)v[1];
        h[2] = (__bf16)v[2]; h[3] = (__bf16)v[3];
        *(bf16x4*)(ab + i * 4) = h;
    }

    for (int t = tid; t < 20480; t += gsz) {
        int j = t & 7, l2 = (t >> 3) & 63, ct = (t >> 9) & 7, kt = t >> 12;
        int k = kt * 32 + (l2 >> 4) * 8 + j;
        int c = ct * 16 + (l2 & 15);
        wf[t] = f2bf(W[k * 128 + c]);
    }
}

// ===========================================================================
// BIG PATH: single GEMM pass writing U (bf16, fragment layout) + stats,
// then a pure streaming activation+segsum kernel.
// ===========================================================================

// k1_single: 256 thr = 4 waves, 1 tile (32 rows)/wave, 128 rows/block.
// grid = E/128 = 12500. LDS = 40 KB W + 1 KB stats -> 3 blocks/CU, 12 waves.
__global__ __launch_bounds__(256, 3) void k1_single(const u16* __restrict__ ab,
                                                    const float* __restrict__ nbr,
                                                    const int* __restrict__ sidx,
                                                    const int* __restrict__ nidx,
                                                    const u16* __restrict__ wf,
                                                    float* __restrict__ sums1,
                                                    u16* __restrict__ U) {
    __shared__ u16 bsm[20480];   // W in fragment order
    __shared__ float bs[256];
    const int tx = threadIdx.x, lane = tx & 63, w = tx >> 6;
    const int mrow = lane & 15, quad = lane >> 4;
    const int blk = blockIdx.x;
    const int rb = blk * 128 + w * 32;

    // Stage W into LDS (independent of the gathers below)
#pragma unroll
    for (int i = 0; i < 10; i++) {
        int idx = (i * 256 + tx) * 8;
        *(bf16x8*)&bsm[idx] = *(const bf16x8*)&wf[idx];
    }
    bs[tx] = 0.0f;

    // Preload ALL A fragments (issues global loads that overlap the LDS
    // staging; the barrier's vmcnt drain collects both).
    const int r0 = rb + mrow, r1 = r0 + 16;
    const int s0 = sidx[r0], s1 = sidx[r1];
    const int n0 = nidx[r0], n1 = nidx[r1];
    const u16* pa0 = ab + s0 * 64 + quad * 8;
    const u16* pa1 = ab + s1 * 64 + quad * 8;
    const u16* pb0 = ab + n0 * 64 + quad * 8;
    const u16* pb1 = ab + n1 * 64 + quad * 8;
    bf16x8 A[5][2];
    A[0][0] = *(const bf16x8*)pa0;        A[0][1] = *(const bf16x8*)pa1;
    A[1][0] = *(const bf16x8*)(pa0 + 32); A[1][1] = *(const bf16x8*)(pa1 + 32);
    A[2][0] = *(const bf16x8*)pb0;        A[2][1] = *(const bf16x8*)pb1;
    A[3][0] = *(const bf16x8*)(pb0 + 32); A[3][1] = *(const bf16x8*)(pb1 + 32);
    {
        const float* p0 = nbr + r0 * 32 + quad * 8;
        const float* p1 = nbr + r1 * 32 + quad * 8;
        A[4][0] = cvt8v(*(const f32x4*)p0, *(const f32x4*)(p0 + 4));
        A[4][1] = cvt8v(*(const f32x4*)p1, *(const f32x4*)(p1 + 4));
    }
    __syncthreads();

    f32x4 acc[2][8];
#pragma unroll
    for (int rf = 0; rf < 2; rf++)
#pragma unroll
        for (int ct = 0; ct < 8; ct++) { f32x4 z = {0.f, 0.f, 0.f, 0.f}; acc[rf][ct] = z; }

#pragma unroll
    for (int kt = 0; kt < 5; kt++) {
#pragma unroll
        for (int ct = 0; ct < 8; ct++) {
            bf16x8 b = *(const bf16x8*)&bsm[((kt * 8 + ct) * 64 + lane) * 8];
            acc[0][ct] = __builtin_amdgcn_mfma_f32_16x16x32_bf16(A[kt][0], b, acc[0][ct], 0, 0, 0);
            acc[1][ct] = __builtin_amdgcn_mfma_f32_16x16x32_bf16(A[kt][1], b, acc[1][ct], 0, 0, 0);
        }
    }

    // U store: fragment layout, chunk c = (blk*4+w)*2+rf covers edges [c*16,c*16+16)
    // addr(u16) = c*2048 + ct*256 + lane*4  -> 512B contiguous per wave-store
#pragma unroll
    for (int rf = 0; rf < 2; rf++) {
        const size_t cbase = ((size_t)(blk * 4 + w) * 2 + rf) * 2048;
#pragma unroll
        for (int ct = 0; ct < 8; ct++) {
            bf16x4 h;
            h[0] = (__bf16)acc[rf][ct][0]; h[1] = (__bf16)acc[rf][ct][1];
            h[2] = (__bf16)acc[rf][ct][2]; h[3] = (__bf16)acc[rf][ct][3];
            *(bf16x4*)(U + cbase + ct * 256 + lane * 4) = h;
        }
    }

    // Stats: C/D col = ct*16+mrow; rows spread over quad (shfl-reduce quads)
#pragma unroll
    for (int ct = 0; ct < 8; ct++) {
        float s = 0.f, q = 0.f;
#pragma unroll
        for (int rf = 0; rf < 2; rf++)
#pragma unroll
            for (int rg = 0; rg < 4; rg++) {
                float v = acc[rf][ct][rg];
                s += v; q += v * v;
            }
        s += __shfl_xor(s, 16, 64); s += __shfl_xor(s, 32, 64);
        q += __shfl_xor(q, 16, 64); q += __shfl_xor(q, 32, 64);
        if (quad == 0) {
            atomicAdd(&bs[ct * 16 + mrow], s);
            atomicAdd(&bs[128 + ct * 16 + mrow], q);
        }
    }
    __syncthreads();
    atomicAdd(&sums1[tx], bs[tx]);
}

// k3_stream: pure streaming BN1+gate+segsum from U. 256 thr = 4 waves, each
// wave scans 4 chunks (64 edges); grid = E/256 = 6250. LDS 16.5 KB -> ~100% occ.
__global__ __launch_bounds__(256) void k3_stream(const u16* __restrict__ U,
                                                 const int* __restrict__ sidx,
                                                 const float* __restrict__ sums1,
                                                 const float* __restrict__ g1,
                                                 const float* __restrict__ b1,
                                                 float* __restrict__ ns) {
    __shared__ float msgb[4][16 * 66];
    const int tx = threadIdx.x, lane = tx & 63, w = tx >> 6;
    const int mrow = lane & 15, quad = lane >> 4;

    const float invE = 1.0f / (float)E_TOT;
    float af[4], kf[4], ac[4], kc[4];
#pragma unroll
    for (int ct = 0; ct < 4; ct++) {
        int cf = ct * 16 + mrow, cc = cf + 64;
        float mf = sums1[cf] * invE;
        float vf = sums1[128 + cf] * invE - mf * mf;
        af[ct] = g1[cf] * rsqrtf(vf + 1e-5f);
        kf[ct] = b1[cf] - af[ct] * mf;
        float mc = sums1[cc] * invE;
        float vc = sums1[128 + cc] * invE - mc * mc;
        ac[ct] = g1[cc] * rsqrtf(vc + 1e-5f);
        kc[ct] = b1[cc] - ac[ct] * mc;
    }

    float* mw = msgb[w];
    const int c0 = blockIdx.x * 16 + w * 4;
#pragma unroll
    for (int cc2 = 0; cc2 < 4; cc2++) {
        const int c = c0 + cc2;
        const size_t cbase = (size_t)c * 2048;
        // load the 16x128 U chunk (same lane mapping as producer)
        bf16x4 uf[8];
#pragma unroll
        for (int ct = 0; ct < 8; ct++)
            uf[ct] = *(const bf16x4*)(U + cbase + ct * 256 + lane * 4);
#pragma unroll
        for (int ct = 0; ct < 4; ct++) {
#pragma unroll
            for (int rg = 0; rg < 4; rg++) {
                float xf = af[ct] * (float)uf[ct][rg] + kf[ct];
                float xc = ac[ct] * (float)uf[ct + 4][rg] + kc[ct];
                float sg = 1.0f / (1.0f + __expf(-xf));
                mw[(quad * 4 + rg) * 66 + ct * 16 + mrow] = sg * softplus_f(xc);
            }
        }
        // same-wave LDS read-back: lane = feature col
        float mv[16];
#pragma unroll
        for (int i = 0; i < 16; i++) mv[i] = mw[i * 66 + lane];
        const int ebase = c * 16;
        float accum = 0.f;
        int cur = sidx[ebase];
#pragma unroll
        for (int i = 0; i < 16; i++) {
            int idx = sidx[ebase + i];
            if (idx != cur) {
                atomicAdd(&ns[cur * 64 + lane], accum);
                accum = 0.f;
                cur = idx;
            }
            accum += mv[i];
        }
        atomicAdd(&ns[cur * 64 + lane], accum);
    }
}

// ===========================================================================
// FALLBACK PATH (ws < 429 MB): round-3 two-pass kernels, verbatim.
// ===========================================================================
__global__ __launch_bounds__(256, 2) void k1_stats(const u16* __restrict__ ab,
                                                   const float* __restrict__ nbr,
                                                   u16* __restrict__ nbrb,
                                                   const int* __restrict__ sidx,
                                                   const int* __restrict__ nidx,
                                                   const u16* __restrict__ wf,
                                                   float* __restrict__ sums1) {
    __shared__ u16 bsm[20480];
    __shared__ float bs[256];
    const int tx = threadIdx.x, lane = tx & 63, w = tx >> 6;
    const int mrow = lane & 15, quad = lane >> 4;
#pragma unroll
    for (int i = 0; i < 10; i++) {
        int idx = (i * 256 + tx) * 8;
        *(bf16x8*)&bsm[idx] = *(const bf16x8*)&wf[idx];
    }
    bs[tx] = 0.0f;
    __syncthreads();

    const int RB = blockIdx.x * 256;
    int rr[2][2];
    const u16* ps[2][2];
    const u16* pn[2][2];
#pragma unroll
    for (int t = 0; t < 2; t++)
#pragma unroll
        for (int rf = 0; rf < 2; rf++) {
            int r = RB + t * 128 + w * 32 + rf * 16 + mrow;
            rr[t][rf] = r;
            ps[t][rf] = ab + sidx[r] * 64 + quad * 8;
            pn[t][rf] = ab + nidx[r] * 64 + quad * 8;
        }
    f32x4 acc[2][2][8];
#pragma unroll
    for (int t = 0; t < 2; t++)
#pragma unroll
        for (int rf = 0; rf < 2; rf++)
#pragma unroll
            for (int ct = 0; ct < 8; ct++) { f32x4 z = {0.f,0.f,0.f,0.f}; acc[t][rf][ct] = z; }
#pragma unroll
    for (int kt = 0; kt < 5; kt++) {
        bf16x8 a[2][2];
#pragma unroll
        for (int t = 0; t < 2; t++)
#pragma unroll
            for (int rf = 0; rf < 2; rf++) {
                if (kt < 2)      a[t][rf] = *(const bf16x8*)(ps[t][rf] + kt * 32);
                else if (kt < 4) a[t][rf] = *(const bf16x8*)(pn[t][rf] + (kt - 2) * 32);
                else {
                    const float* p = nbr + rr[t][rf] * 32 + quad * 8;
                    bf16x8 av = cvt8v(*(const f32x4*)p, *(const f32x4*)(p + 4));
                    *(bf16x8*)(nbrb + rr[t][rf] * 32 + quad * 8) = av;
                    a[t][rf] = av;
                }
            }
#pragma unroll
        for (int ct = 0; ct < 8; ct++) {
            bf16x8 b = *(const bf16x8*)&bsm[((kt * 8 + ct) * 64 + lane) * 8];
            acc[0][0][ct] = __builtin_amdgcn_mfma_f32_16x16x32_bf16(a[0][0], b, acc[0][0][ct], 0, 0, 0);
            acc[0][1][ct] = __builtin_amdgcn_mfma_f32_16x16x32_bf16(a[0][1], b, acc[0][1][ct], 0, 0, 0);
            acc[1][0][ct] = __builtin_amdgcn_mfma_f32_16x16x32_bf16(a[1][0], b, acc[1][0][ct], 0, 0, 0);
            acc[1][1][ct] = __builtin_amdgcn_mfma_f32_16x16x32_bf16(a[1][1], b, acc[1][1][ct], 0, 0, 0);
        }
    }
#pragma unroll
    for (int ct = 0; ct < 8; ct++) {
        float s = 0.f, q = 0.f;
#pragma unroll
        for (int t = 0; t < 2; t++)
#pragma unroll
            for (int rf = 0; rf < 2; rf++)
#pragma unroll
                for (int rg = 0; rg < 4; rg++) { float v = acc[t][rf][ct][rg]; s += v; q += v * v; }
        s += __shfl_xor(s, 16, 64); s += __shfl_xor(s, 32, 64);
        q += __shfl_xor(q, 16, 64); q += __shfl_xor(q, 32, 64);
        if (quad == 0) {
            atomicAdd(&bs[ct * 16 + mrow], s);
            atomicAdd(&bs[128 + ct * 16 + mrow], q);
        }
    }
    __syncthreads();
    atomicAdd(&sums1[tx], bs[tx]);
}

__global__ __launch_bounds__(256, 2) void k3_msg(const u16* __restrict__ ab,
                                                 const u16* __restrict__ nbrb,
                                                 const int* __restrict__ sidx,
                                                 const int* __restrict__ nidx,
                                                 const u16* __restrict__ wf,
                                                 const float* __restrict__ sums1,
                                                 const float* __restrict__ g1,
                                                 const float* __restrict__ b1,
                                                 float* __restrict__ ns) {
    __shared__ u16 bsm[20480];
    __shared__ float msg[4][16 * 66];
    const int tx = threadIdx.x, lane = tx & 63, w = tx >> 6;
    const int mrow = lane & 15, quad = lane >> 4;
#pragma unroll
    for (int i = 0; i < 10; i++) {
        int idx = (i * 256 + tx) * 8;
        *(bf16x8*)&bsm[idx] = *(const bf16x8*)&wf[idx];
    }
    __syncthreads();

    const float invE = 1.0f / (float)E_TOT;
    float af[4], kf[4], ac[4], kc[4];
#pragma unroll
    for (int ct = 0; ct < 4; ct++) {
        int cf = ct * 16 + mrow, cc = cf + 64;
        float mf = sums1[cf] * invE;
        float vf = sums1[128 + cf] * invE - mf * mf;
        af[ct] = g1[cf] * rsqrtf(vf + 1e-5f);
        kf[ct] = b1[cf] - af[ct] * mf;
        float mc = sums1[cc] * invE;
        float vc = sums1[128 + cc] * invE - mc * mc;
        ac[ct] = g1[cc] * rsqrtf(vc + 1e-5f);
        kc[ct] = b1[cc] - ac[ct] * mc;
    }

    const int RB = blockIdx.x * 256;
    int rr[2][2];
    const u16* ps[2][2];
    const u16* pn[2][2];
#pragma unroll
    for (int t = 0; t < 2; t++)
#pragma unroll
        for (int rf = 0; rf < 2; rf++) {
            int r = RB + t * 128 + w * 32 + rf * 16 + mrow;
            rr[t][rf] = r;
            ps[t][rf] = ab + sidx[r] * 64 + quad * 8;
            pn[t][rf] = ab + nidx[r] * 64 + quad * 8;
        }
    f32x4 acc[2][2][8];
#pragma unroll
    for (int t = 0; t < 2; t++)
#pragma unroll
        for (int rf = 0; rf < 2; rf++)
#pragma unroll
            for (int ct = 0; ct < 8; ct++) { f32x4 z = {0.f,0.f,0.f,0.f}; acc[t][rf][ct] = z; }
#pragma unroll
    for (int kt = 0; kt < 5; kt++) {
        bf16x8 a[2][2];
#pragma unroll
        for (int t = 0; t < 2; t++)
#pragma unroll
            for (int rf = 0; rf < 2; rf++) {
                if (kt < 2)      a[t][rf] = *(const bf16x8*)(ps[t][rf] + kt * 32);
                else if (kt < 4) a[t][rf] = *(const bf16x8*)(pn[t][rf] + (kt - 2) * 32);
                else             a[t][rf] = *(const bf16x8*)(nbrb + rr[t][rf] * 32 + quad * 8);
            }
#pragma unroll
        for (int ct = 0; ct < 8; ct++) {
            bf16x8 b = *(const bf16x8*)&bsm[((kt * 8 + ct) * 64 + lane) * 8];
            acc[0][0][ct] = __builtin_amdgcn_mfma_f32_16x16x32_bf16(a[0][0], b, acc[0][0][ct], 0, 0, 0);
            acc[0][1][ct] = __builtin_amdgcn_mfma_f32_16x16x32_bf16(a[0][1], b, acc[0][1][ct], 0, 0, 0);
            acc[1][0][ct] = __builtin_amdgcn_mfma_f32_16x16x32_bf16(a[1][0], b, acc[1][0][ct], 0, 0, 0);
            acc[1][1][ct] = __builtin_amdgcn_mfma_f32_16x16x32_bf16(a[1][1], b, acc[1][1][ct], 0, 0, 0);
        }
    }
    float* mw = msg[w];
#pragma unroll
    for (int t = 0; t < 2; t++) {
#pragma unroll
        for (int rf = 0; rf < 2; rf++) {
#pragma unroll
            for (int ct = 0; ct < 4; ct++) {
#pragma unroll
                for (int rg = 0; rg < 4; rg++) {
                    float xf = af[ct] * acc[t][rf][ct][rg] + kf[ct];
                    float xc = ac[ct] * acc[t][rf][ct + 4][rg] + kc[ct];
                    float sg = 1.0f / (1.0f + __expf(-xf));
                    mw[(quad * 4 + rg) * 66 + ct * 16 + mrow] = sg * softplus_f(xc);
                }
            }
            const int ebase = RB + t * 128 + w * 32 + rf * 16;
            float mv[16];
#pragma unroll
            for (int i = 0; i < 16; i++) mv[i] = mw[i * 66 + lane];
            float accum = 0.f;
            int cur = sidx[ebase];
#pragma unroll
            for (int i = 0; i < 16; i++) {
                int idx = sidx[ebase + i];
                if (idx != cur) {
                    atomicAdd(&ns[cur * 64 + lane], accum);
                    accum = 0.f;
                    cur = idx;
                }
                accum += mv[i];
            }
            atomicAdd(&ns[cur * 64 + lane], accum);
        }
    }
}

// ---------------------------------------------------------------------------
// k4: BN2 stats over nbr_sumed (N x 64 f32) -> sums2[128]
// ---------------------------------------------------------------------------
__global__ __launch_bounds__(256) void k4_bn2stats(const float* __restrict__ ns,
                                                   float* __restrict__ sums2) {
    const int tx = threadIdx.x;
    const int col = tx & 63, rg = tx >> 6;
    float s = 0.f, q = 0.f;
    for (int r = blockIdx.x * 4 + rg; r < N_AT; r += 256 * 4) {
        float v = ns[r * 64 + col];
        s += v; q += v * v;
    }
    atomicAdd(&sums2[col], s);
    atomicAdd(&sums2[64 + col], q);
}

// ---------------------------------------------------------------------------
// k5: out = softplus(atom + BN2(nbr_sumed))
// ---------------------------------------------------------------------------
__global__ __launch_bounds__(256) void k5_final(const float* __restrict__ atom,
                                                const float* __restrict__ ns,
                                                const float* __restrict__ sums2,
                                                const float* __restrict__ g2,
                                                const float* __restrict__ b2,
                                                float* __restrict__ out) {
    const int i = blockIdx.x * 256 + threadIdx.x;
    const int col = i & 63;
    const float invN = 1.0f / (float)N_AT;
    float mean = sums2[col] * invN;
    float var = sums2[64 + col] * invN - mean * mean;
    float a2 = g2[col] * rsqrtf(var + 1e-5f);
    float c2 = b2[col] - a2 * mean;
    out[i] = softplus_f(atom[i] + a2 * ns[i] + c2);
}

extern "C" void kernel_launch(void* const* d_in, const int* in_sizes, int n_in,
                              void* d_out, int out_size, void* d_ws, size_t ws_size,
                              hipStream_t stream) {
    const float* atom = (const float*)d_in[0];
    const float* nbr  = (const float*)d_in[1];
    const int* sidx   = (const int*)d_in[2];
    const int* nidx   = (const int*)d_in[3];
    const float* W    = (const float*)d_in[4];
    // d_in[5] = b : cancels exactly under training-mode BN1 -> unused
    const float* g1   = (const float*)d_in[6];
    const float* b1   = (const float*)d_in[7];
    const float* g2   = (const float*)d_in[8];
    const float* b2   = (const float*)d_in[9];
    float* out = (float*)d_out;

    char* ws = (char*)d_ws;
    float* sums1 = (float*)(ws + SUM1_OFF);
    float* sums2 = (float*)(ws + SUM2_OFF);
    u16*   wf    = (u16*)(ws + WF_OFF);
    float* nsum  = (float*)(ws + NS_OFF);
    u16*   ab    = (u16*)(ws + AB_OFF);
    u16*   Ubuf  = (u16*)(ws + U_OFF);
    u16*   nbrb  = (u16*)(ws + NBRB_OFF);

    const bool big = ws_size >= (size_t)WS_BIG;  // deterministic per process

    k_setup<<<1024, 256, 0, stream>>>(atom, W, ws);
    if (big) {
        k1_single<<<E_TOT / 128, 256, 0, stream>>>(ab, nbr, sidx, nidx, wf, sums1, Ubuf);
        k3_stream<<<E_TOT / 256, 256, 0, stream>>>(Ubuf, sidx, sums1, g1, b1, nsum);
    } else {
        k1_stats<<<E_TOT / 256, 256, 0, stream>>>(ab, nbr, nbrb, sidx, nidx, wf, sums1);
        k3_msg<<<E_TOT / 256, 256, 0, stream>>>(ab, nbrb, sidx, nidx, wf, sums1, g1, b1, nsum);
    }
    k4_bn2stats<<<256, 256, 0, stream>>>(nsum, sums2);
    k5_final<<<(N_AT * 64) / 256, 256, 0, stream>>>(atom, nsum, sums2, g2, b2, out);
}

// Round 5
// 733.429 us; speedup vs baseline: 1.0284x; 1.0284x over previous
//
#include <hip/hip_runtime.h>

#define E_TOT 1600000
#define N_AT  50000

typedef unsigned short u16;
typedef __attribute__((ext_vector_type(8))) __bf16 bf16x8;
typedef __attribute__((ext_vector_type(4))) __bf16 bf16x4;
typedef __attribute__((ext_vector_type(4))) float f32x4;

// Workspace layout (byte offsets), all 16B-aligned (ws >= 429 MB proven in R4):
//   [0,       1024)   sums1 (256 f32)  -- zeroed by k_setup
//   [1024,    1536)   sums2 (128 f32)  -- zeroed by k_setup
//   [2048,   43008)   wf    (20480 bf16, B-fragment order) -- written by k_setup
//   [43008, +12.8M)   ns    (N*64 f32) -- zeroed by k_setup
//   [+,      +6.4M)   ab    (N*64 bf16) -- written by k_setup
//   [+,    +102.4M)   nbrb  (E*32 bf16) -- written by k1
#define SUM1_OFF 0
#define SUM2_OFF 1024
#define WF_OFF   2048
#define NS_OFF   43008
#define AB_OFF   12843008
#define NBRB_OFF 19243008

__device__ __forceinline__ u16 f2bf(float f) {
    unsigned int u = __float_as_uint(f);
    return (u16)((u + 0x7FFFu + ((u >> 16) & 1u)) >> 16);
}
__device__ __forceinline__ float softplus_f(float x) {
    return fmaxf(x, 0.0f) + __logf(1.0f + __expf(-fabsf(x)));
}
__device__ __forceinline__ bf16x8 cvt8v(f32x4 a, f32x4 b) {
    bf16x8 r;
    r[0] = (__bf16)a[0]; r[1] = (__bf16)a[1]; r[2] = (__bf16)a[2]; r[3] = (__bf16)a[3];
    r[4] = (__bf16)b[0]; r[5] = (__bf16)b[1]; r[6] = (__bf16)b[2]; r[7] = (__bf16)b[3];
    return r;
}

// ---------------------------------------------------------------------------
// k_setup: zero sums1/sums2/ns + cvt atom->ab + swizzle W->wf
// ---------------------------------------------------------------------------
__global__ __launch_bounds__(256) void k_setup(const float* __restrict__ atom,
                                               const float* __restrict__ W,
                                               char* __restrict__ ws) {
    u16* wf   = (u16*)(ws + WF_OFF);
    float* ns = (float*)(ws + NS_OFF);
    u16* ab   = (u16*)(ws + AB_OFF);
    const int tid = blockIdx.x * 256 + threadIdx.x;
    const int gsz = gridDim.x * 256;

    for (int i = tid; i < 512; i += gsz) ((float*)ws)[i] = 0.0f;  // sums1+sums2

    f32x4 z = {0.f, 0.f, 0.f, 0.f};
    for (int i = tid; i < N_AT * 64 / 4; i += gsz) ((f32x4*)ns)[i] = z;

    for (int i = tid; i < N_AT * 64 / 4; i += gsz) {
        f32x4 v = ((const f32x4*)atom)[i];
        bf16x4 h;
        h[0] = (__bf16)v[0]; h[1] = (__bf16)v[1];
        h[2] = (__bf16)v[2]; h[3] = (__bf16)v[3];
        *(bf16x4*)(ab + i * 4) = h;
    }

    for (int t = tid; t < 20480; t += gsz) {
        int j = t & 7, l2 = (t >> 3) & 63, ct = (t >> 9) & 7, kt = t >> 12;
        int k = kt * 32 + (l2 >> 4) * 8 + j;
        int c = ct * 16 + (l2 & 15);
        wf[t] = f2bf(W[k * 128 + c]);
    }
}

// ---------------------------------------------------------------------------
// k1: GEMM pass 1 (stats) + nbr->bf16 cvt. 512 thr = 8 waves, 32 rows/wave,
// 256 rows/block, grid = E/256. LDS = 40KB W + 1KB -> 2 blocks/CU, 16 waves.
// ---------------------------------------------------------------------------
__global__ __launch_bounds__(512, 4) void k1_stats(const u16* __restrict__ ab,
                                                   const float* __restrict__ nbr,
                                                   u16* __restrict__ nbrb,
                                                   const int* __restrict__ sidx,
                                                   const int* __restrict__ nidx,
                                                   const u16* __restrict__ wf,
                                                   float* __restrict__ sums1) {
    __shared__ u16 bsm[20480];   // W in fragment order (40 KB)
    __shared__ float bs[256];
    const int tx = threadIdx.x, lane = tx & 63, w = tx >> 6;
    const int mrow = lane & 15, quad = lane >> 4;

#pragma unroll
    for (int i = 0; i < 5; i++) {
        int idx = (i * 512 + tx) * 8;    // 8 KB per block-wide iteration
        *(bf16x8*)&bsm[idx] = *(const bf16x8*)&wf[idx];
    }
    if (tx < 256) bs[tx] = 0.0f;

    const int rb = blockIdx.x * 256 + w * 32;
    const int r0 = rb + mrow, r1 = r0 + 16;
    const int s0 = sidx[r0], s1 = sidx[r1];
    const int n0 = nidx[r0], n1 = nidx[r1];
    const u16* pa0 = ab + (size_t)s0 * 64 + quad * 8;
    const u16* pa1 = ab + (size_t)s1 * 64 + quad * 8;
    const u16* pb0 = ab + (size_t)n0 * 64 + quad * 8;
    const u16* pb1 = ab + (size_t)n1 * 64 + quad * 8;
    __syncthreads();

    f32x4 acc[2][8];
#pragma unroll
    for (int rf = 0; rf < 2; rf++)
#pragma unroll
        for (int ct = 0; ct < 8; ct++) { f32x4 z = {0.f, 0.f, 0.f, 0.f}; acc[rf][ct] = z; }

#pragma unroll
    for (int kt = 0; kt < 5; kt++) {
        bf16x8 a0, a1;
        if (kt < 2) {
            a0 = *(const bf16x8*)(pa0 + kt * 32);
            a1 = *(const bf16x8*)(pa1 + kt * 32);
        } else if (kt < 4) {
            a0 = *(const bf16x8*)(pb0 + (kt - 2) * 32);
            a1 = *(const bf16x8*)(pb1 + (kt - 2) * 32);
        } else {
            const float* p0 = nbr + (size_t)r0 * 32 + quad * 8;
            const float* p1 = nbr + (size_t)r1 * 32 + quad * 8;
            a0 = cvt8v(*(const f32x4*)p0, *(const f32x4*)(p0 + 4));
            a1 = cvt8v(*(const f32x4*)p1, *(const f32x4*)(p1 + 4));
            *(bf16x8*)(nbrb + (size_t)r0 * 32 + quad * 8) = a0;
            *(bf16x8*)(nbrb + (size_t)r1 * 32 + quad * 8) = a1;
        }
#pragma unroll
        for (int ct = 0; ct < 8; ct++) {
            bf16x8 b = *(const bf16x8*)&bsm[((kt * 8 + ct) * 64 + lane) * 8];
            acc[0][ct] = __builtin_amdgcn_mfma_f32_16x16x32_bf16(a0, b, acc[0][ct], 0, 0, 0);
            acc[1][ct] = __builtin_amdgcn_mfma_f32_16x16x32_bf16(a1, b, acc[1][ct], 0, 0, 0);
        }
    }

    // Stats: C/D col = ct*16+mrow; reduce rows over quads via shfl
#pragma unroll
    for (int ct = 0; ct < 8; ct++) {
        float s = 0.f, q = 0.f;
#pragma unroll
        for (int rf = 0; rf < 2; rf++)
#pragma unroll
            for (int rg = 0; rg < 4; rg++) {
                float v = acc[rf][ct][rg];
                s += v; q += v * v;
            }
        s += __shfl_xor(s, 16, 64); s += __shfl_xor(s, 32, 64);
        q += __shfl_xor(q, 16, 64); q += __shfl_xor(q, 32, 64);
        if (quad == 0) {
            atomicAdd(&bs[ct * 16 + mrow], s);
            atomicAdd(&bs[128 + ct * 16 + mrow], q);
        }
    }
    __syncthreads();
    if (tx < 256) atomicAdd(&sums1[tx], bs[tx]);
}

// ---------------------------------------------------------------------------
// k3: GEMM pass 2 + BN1 + sigmoid*softplus + segment-sum. 512 thr = 8 waves,
// 32 rows/wave. LDS = 40KB W + 33.8KB msg -> 2 blocks/CU, 16 waves (50%).
// ---------------------------------------------------------------------------
__global__ __launch_bounds__(512, 4) void k3_msg(const u16* __restrict__ ab,
                                                 const u16* __restrict__ nbrb,
                                                 const int* __restrict__ sidx,
                                                 const int* __restrict__ nidx,
                                                 const u16* __restrict__ wf,
                                                 const float* __restrict__ sums1,
                                                 const float* __restrict__ g1,
                                                 const float* __restrict__ b1,
                                                 float* __restrict__ ns) {
    __shared__ u16 bsm[20480];          // 40 KB
    __shared__ float msgb[8][16 * 66];  // 33.8 KB, per-wave region
    const int tx = threadIdx.x, lane = tx & 63, w = tx >> 6;
    const int mrow = lane & 15, quad = lane >> 4;

#pragma unroll
    for (int i = 0; i < 5; i++) {
        int idx = (i * 512 + tx) * 8;
        *(bf16x8*)&bsm[idx] = *(const bf16x8*)&wf[idx];
    }

    const int rb = blockIdx.x * 256 + w * 32;
    const int r0 = rb + mrow, r1 = r0 + 16;
    const int s0 = sidx[r0], s1 = sidx[r1];
    const int n0 = nidx[r0], n1 = nidx[r1];
    const u16* pa0 = ab + (size_t)s0 * 64 + quad * 8;
    const u16* pa1 = ab + (size_t)s1 * 64 + quad * 8;
    const u16* pb0 = ab + (size_t)n0 * 64 + quad * 8;
    const u16* pb1 = ab + (size_t)n1 * 64 + quad * 8;
    __syncthreads();

    f32x4 acc[2][8];
#pragma unroll
    for (int rf = 0; rf < 2; rf++)
#pragma unroll
        for (int ct = 0; ct < 8; ct++) { f32x4 z = {0.f, 0.f, 0.f, 0.f}; acc[rf][ct] = z; }

#pragma unroll
    for (int kt = 0; kt < 5; kt++) {
        bf16x8 a0, a1;
        if (kt < 2) {
            a0 = *(const bf16x8*)(pa0 + kt * 32);
            a1 = *(const bf16x8*)(pa1 + kt * 32);
        } else if (kt < 4) {
            a0 = *(const bf16x8*)(pb0 + (kt - 2) * 32);
            a1 = *(const bf16x8*)(pb1 + (kt - 2) * 32);
        } else {
            a0 = *(const bf16x8*)(nbrb + (size_t)r0 * 32 + quad * 8);
            a1 = *(const bf16x8*)(nbrb + (size_t)r1 * 32 + quad * 8);
        }
#pragma unroll
        for (int ct = 0; ct < 8; ct++) {
            bf16x8 b = *(const bf16x8*)&bsm[((kt * 8 + ct) * 64 + lane) * 8];
            acc[0][ct] = __builtin_amdgcn_mfma_f32_16x16x32_bf16(a0, b, acc[0][ct], 0, 0, 0);
            acc[1][ct] = __builtin_amdgcn_mfma_f32_16x16x32_bf16(a1, b, acc[1][ct], 0, 0, 0);
        }
    }

    // BN1 affine constants (computed AFTER the GEMM so they're not live above;
    // fc bias b cancels exactly under training-mode BN)
    const float invE = 1.0f / (float)E_TOT;
    float af[4], kf[4], ac[4], kc[4];
#pragma unroll
    for (int ct = 0; ct < 4; ct++) {
        int cf = ct * 16 + mrow, cc = cf + 64;
        float mf = sums1[cf] * invE;
        float vf = sums1[128 + cf] * invE - mf * mf;
        af[ct] = g1[cf] * rsqrtf(vf + 1e-5f);
        kf[ct] = b1[cf] - af[ct] * mf;
        float mc = sums1[cc] * invE;
        float vc = sums1[128 + cc] * invE - mc * mc;
        ac[ct] = g1[cc] * rsqrtf(vc + 1e-5f);
        kc[ct] = b1[cc] - ac[ct] * mc;
    }

    // Epilogue per 16-row half-tile: gate -> same-wave LDS transpose -> scan
    float* mw = msgb[w];
#pragma unroll
    for (int rf = 0; rf < 2; rf++) {
#pragma unroll
        for (int ct = 0; ct < 4; ct++) {
#pragma unroll
            for (int rg = 0; rg < 4; rg++) {
                // C/D layout: row = quad*4+rg (+16*rf), col = mrow (+16*ct)
                float xf = af[ct] * acc[rf][ct][rg] + kf[ct];
                float xc = ac[ct] * acc[rf][ct + 4][rg] + kc[ct];
                float sg = 1.0f / (1.0f + __expf(-xf));
                mw[(quad * 4 + rg) * 66 + ct * 16 + mrow] = sg * softplus_f(xc);
            }
        }
        const int ebase = rb + rf * 16;
        float mv[16];
#pragma unroll
        for (int i = 0; i < 16; i++) mv[i] = mw[i * 66 + lane];
        float accum = 0.f;
        int cur = sidx[ebase];
#pragma unroll
        for (int i = 0; i < 16; i++) {
            int idx = sidx[ebase + i];   // wave-uniform -> scalar loads
            if (idx != cur) {
                atomicAdd(&ns[(size_t)cur * 64 + lane], accum);
                accum = 0.f;
                cur = idx;
            }
            accum += mv[i];
        }
        atomicAdd(&ns[(size_t)cur * 64 + lane], accum);
    }
}

// ---------------------------------------------------------------------------
// k4: BN2 stats over nbr_sumed (N x 64 f32) -> sums2[128]
// ---------------------------------------------------------------------------
__global__ __launch_bounds__(256) void k4_bn2stats(const float* __restrict__ ns,
                                                   float* __restrict__ sums2) {
    const int tx = threadIdx.x;
    const int col = tx & 63, rg = tx >> 6;
    float s = 0.f, q = 0.f;
    for (int r = blockIdx.x * 4 + rg; r < N_AT; r += 256 * 4) {
        float v = ns[r * 64 + col];
        s += v; q += v * v;
    }
    atomicAdd(&sums2[col], s);
    atomicAdd(&sums2[64 + col], q);
}

// ---------------------------------------------------------------------------
// k5: out = softplus(atom + BN2(nbr_sumed))
// ---------------------------------------------------------------------------
__global__ __launch_bounds__(256) void k5_final(const float* __restrict__ atom,
                                                const float* __restrict__ ns,
                                                const float* __restrict__ sums2,
                                                const float* __restrict__ g2,
                                                const float* __restrict__ b2,
                                                float* __restrict__ out) {
    const int i = blockIdx.x * 256 + threadIdx.x;  // grid covers N*64 exactly
    const int col = i & 63;
    const float invN = 1.0f / (float)N_AT;
    float mean = sums2[col] * invN;
    float var = sums2[64 + col] * invN - mean * mean;
    float a2 = g2[col] * rsqrtf(var + 1e-5f);
    float c2 = b2[col] - a2 * mean;
    out[i] = softplus_f(atom[i] + a2 * ns[i] + c2);
}

extern "C" void kernel_launch(void* const* d_in, const int* in_sizes, int n_in,
                              void* d_out, int out_size, void* d_ws, size_t ws_size,
                              hipStream_t stream) {
    const float* atom = (const float*)d_in[0];
    const float* nbr  = (const float*)d_in[1];
    const int* sidx   = (const int*)d_in[2];
    const int* nidx   = (const int*)d_in[3];
    const float* W    = (const float*)d_in[4];
    // d_in[5] = b : cancels exactly under training-mode BN1 -> unused
    const float* g1   = (const float*)d_in[6];
    const float* b1   = (const float*)d_in[7];
    const float* g2   = (const float*)d_in[8];
    const float* b2   = (const float*)d_in[9];
    float* out = (float*)d_out;

    char* ws = (char*)d_ws;
    float* sums1 = (float*)(ws + SUM1_OFF);
    float* sums2 = (float*)(ws + SUM2_OFF);
    u16*   wf    = (u16*)(ws + WF_OFF);
    float* nsum  = (float*)(ws + NS_OFF);
    u16*   ab    = (u16*)(ws + AB_OFF);
    u16*   nbrb  = (u16*)(ws + NBRB_OFF);

    k_setup<<<1024, 256, 0, stream>>>(atom, W, ws);
    k1_stats<<<E_TOT / 256, 512, 0, stream>>>(ab, nbr, nbrb, sidx, nidx, wf, sums1);
    k3_msg<<<E_TOT / 256, 512, 0, stream>>>(ab, nbrb, sidx, nidx, wf, sums1, g1, b1, nsum);
    k4_bn2stats<<<256, 256, 0, stream>>>(nsum, sums2);
    k5_final<<<(N_AT * 64) / 256, 256, 0, stream>>>(atom, nsum, sums2, g2, b2, out);
}